// Round 8
// baseline (301.644 us; speedup 1.0000x reference)
//
#include <hip/hip_runtime.h>
#include <hip/hip_bf16.h>
#include <stdint.h>

// EvolvedLoopLinear: out[b,j] = sum_i x[b,i]*W[j,i] + b[j]
// M=8192, N=4096, K=4096. fp32 in/out, bf16 MFMA compute.
// Round 8: round-6 schedule (1 barrier/phase, counted vmcnt(6), XOR chunk
// swizzle, XCD swizzle, setprio) with MFMA shape switched to
// 32x32x16_bf16 (4060 FLOP/cyc vs 3378 for 16x16x32, m119). Same LDS
// bytes, same fragment/acc register footprint, half the MFMA instrs.
// A-frag: row = l&31, k0 = (l>>5)*8 (analog of verified 16x16 mapping);
// C/D: col = l&31, row = (reg&3) + 8*(reg>>2) + 4*(l>>5)  [m74/m101].

typedef __bf16 bf16_t;
typedef __bf16 bf16x8 __attribute__((ext_vector_type(8)));
typedef float  f32x16 __attribute__((ext_vector_type(16)));

#define M_DIM 8192
#define N_DIM 4096
#define K_DIM 4096
#define NT    (K_DIM / 64)    // 64 K-tiles of BK=64
#define NITER (NT / 2)        // 32 iterations, 2 K-tiles each

#define GLD16(gp, lp) __builtin_amdgcn_global_load_lds(                    \
    (const __attribute__((address_space(1))) void*)(gp),                   \
    (__attribute__((address_space(3))) void*)(lp), 16, 0, 0)

#define MFMA32(a, b, c) __builtin_amdgcn_mfma_f32_32x32x16_bf16((a), (b), (c), 0, 0, 0)

#define FENCE() asm volatile("" ::: "memory")

// ---------------- fp32 -> bf16 convert (vectorized, grid-stride) -----------
__global__ void __launch_bounds__(256) cvt_f32_bf16(
    const float* __restrict__ in, bf16_t* __restrict__ out, long n8)
{
    long i0 = (long)blockIdx.x * blockDim.x + threadIdx.x;
    long stride = (long)gridDim.x * blockDim.x;
    for (long i = i0; i < n8; i += stride) {
        const float4* p = (const float4*)(in + i * 8);
        float4 a = p[0];
        float4 b = p[1];
        bf16x8 o;
        o[0] = (bf16_t)a.x; o[1] = (bf16_t)a.y; o[2] = (bf16_t)a.z; o[3] = (bf16_t)a.w;
        o[4] = (bf16_t)b.x; o[5] = (bf16_t)b.y; o[6] = (bf16_t)b.z; o[7] = (bf16_t)b.w;
        *(bf16x8*)(out + i * 8) = o;
    }
}

// ---------------- 256x256 8-phase bf16 GEMM (A,B row-major [*,K]) ----------
// LDS per parity buffer q (32768 el): Am0 @0, Am1 @8192, Bn0 @16384,
// Bn1 @24576. Region rho-rows as in round 5/6; chunk swizzle within each
// region: slot = chunk ^ (rho&7) on 16B granules.
__global__ void __launch_bounds__(512, 1) gemm_256_8ph(
    const bf16_t* __restrict__ A, const bf16_t* __restrict__ B,
    const float* __restrict__ bias, float* __restrict__ C)
{
    __shared__ bf16_t sm[2 * 32768];   // 128 KiB

    // XCD-aware bijective swizzle (gridDim = 512, divisible by 8)
    const int nwg = gridDim.x;
    const int bid = blockIdx.x;
    const int cpx = nwg >> 3;
    const int swz = (bid & 7) * cpx + (bid >> 3);
    const int NBN = N_DIM / 256;                       // 16
    const long blockM = (long)(swz / NBN) * 256;
    const long blockN = (long)(swz % NBN) * 256;

    const int t    = threadIdx.x;
    const int lane = t & 63;
    const int wid  = t >> 6;        // 8 waves: 2 (M) x 4 (N)
    const int wr   = wid >> 2;      // 0..1 -> 128 rows each
    const int wc   = wid & 3;       // 0..3 -> 64 cols each
    const int l31  = lane & 31;
    const int hi   = lane >> 5;     // 0..1

    // staging: LDS dest linear (t*16B within region line); global src row
    // per region mapping, chunk carries inverse swizzle. (unchanged)
    const int cg  = (t & 7) ^ ((t >> 3) & 7);
    const int rA0 = (t >> 3);                                  // A line-0 row
    const int rB0 = ((t >> 3) & 31) | (((t >> 3) & 32) << 1);  // B line-0 row
    const bf16_t* gA = A + (blockM + rA0) * (long)K_DIM + cg * 8;
    const bf16_t* gB = B + (blockN + rB0) * (long)K_DIM + cg * 8;
    const int dstT = t * 8;         // 16 B per thread, linear within line

    // read side (32x32x16 fragments): lane reads row l31 of its tile,
    // k-chunk = K*2 + hi, swizzled slot = chunk ^ (l31&7).
    const int swzl = l31 & 7;
    int cOffK[4];
#pragma unroll
    for (int K = 0; K < 4; ++K) cOffK[K] = ((K * 2 + hi) ^ swzl) << 3;
    const int aBase = wr * 4096 + l31 * 64;            // within Am region
    const int bBase = 16384 + wc * 2048 + l31 * 64;    // within buffer (Bn0)

    f32x16 acc[4][2] = {};   // [m-tile 32r][n-tile 32c]

#define STAGE_A(q, tk, h) do {                                             \
    const bf16_t* _g = gA + (long)(tk) * 64 + (long)(h) * 64 * K_DIM;      \
    bf16_t* _l = (bf16_t*)sm + (q) * 32768 + (h) * 8192 + dstT;            \
    GLD16(_g,                _l);                                          \
    GLD16(_g + 128L * K_DIM, _l + 4096); } while (0)

#define STAGE_B(q, tk, h) do {                                             \
    const bf16_t* _g = gB + (long)(tk) * 64 + (long)(h) * 32 * K_DIM;      \
    bf16_t* _l = (bf16_t*)sm + (q) * 32768 + 16384 + (h) * 8192 + dstT;    \
    GLD16(_g,                _l);                                          \
    GLD16(_g + 128L * K_DIM, _l + 4096); } while (0)

    bf16x8 a0[2][4], a1[2][4], b0[4], b1[4];  // [m-local][kstep] / [kstep]

#define READ_A0B0(s) do {                                                  \
    _Pragma("unroll") for (int m = 0; m < 2; ++m)                          \
    _Pragma("unroll") for (int K = 0; K < 4; ++K)                          \
        a0[m][K] = *(const bf16x8*)((s) + aBase + m * 2048 + cOffK[K]);    \
    _Pragma("unroll") for (int K = 0; K < 4; ++K)                          \
        b0[K] = *(const bf16x8*)((s) + bBase + cOffK[K]); } while (0)

#define READ_B1(s) do {                                                    \
    _Pragma("unroll") for (int K = 0; K < 4; ++K)                          \
        b1[K] = *(const bf16x8*)((s) + bBase + 8192 + cOffK[K]); } while (0)

#define READ_A1(s) do {                                                    \
    _Pragma("unroll") for (int m = 0; m < 2; ++m)                          \
    _Pragma("unroll") for (int K = 0; K < 4; ++K)                          \
        a1[m][K] = *(const bf16x8*)((s) + 8192 + aBase + m * 2048 + cOffK[K]); } while (0)

    // 8 MFMA per quadrant-phase (vs 16 with 16x16x32)
#define MFMA_Q0() do { _Pragma("unroll") for (int K = 0; K < 4; ++K)       \
    _Pragma("unroll") for (int m = 0; m < 2; ++m)                          \
        acc[m][0] = MFMA32(a0[m][K], b0[K], acc[m][0]); } while (0)
#define MFMA_Q1() do { _Pragma("unroll") for (int K = 0; K < 4; ++K)       \
    _Pragma("unroll") for (int m = 0; m < 2; ++m)                          \
        acc[m][1] = MFMA32(a0[m][K], b1[K], acc[m][1]); } while (0)
#define MFMA_Q2() do { _Pragma("unroll") for (int K = 0; K < 4; ++K)       \
    _Pragma("unroll") for (int m = 0; m < 2; ++m)                          \
        acc[2 + m][0] = MFMA32(a1[m][K], b0[K], acc[2 + m][0]); } while (0)
#define MFMA_Q3() do { _Pragma("unroll") for (int K = 0; K < 4; ++K)       \
    _Pragma("unroll") for (int m = 0; m < 2; ++m)                          \
        acc[2 + m][1] = MFMA32(a1[m][K], b1[K], acc[2 + m][1]); } while (0)

#define LGKM_SB()                                                          \
    asm volatile("s_waitcnt lgkmcnt(0)" ::: "memory");                     \
    __builtin_amdgcn_sched_barrier(0)

#define END_BARRIER()                                                      \
    __builtin_amdgcn_s_barrier();                                          \
    FENCE()

    // prologue: tile0 all 4 regions (8 loads) | tile1 minus Am1 (6 loads).
    STAGE_A(0, 0, 0); STAGE_A(0, 0, 1); STAGE_B(0, 0, 0); STAGE_B(0, 0, 1);
    FENCE();
    STAGE_A(1, 1, 0); STAGE_B(1, 1, 0); STAGE_B(1, 1, 1);
    FENCE();
    asm volatile("s_waitcnt vmcnt(6)" ::: "memory");   // tile0 landed
    __builtin_amdgcn_sched_barrier(0);
    END_BARRIER();

    const bf16_t* s0 = (const bf16_t*)sm;           // buf0 (even tiles)
    const bf16_t* s1 = (const bf16_t*)sm + 32768;   // buf1 (odd tiles)

    for (int i = 0; i < NITER; ++i) {
        const int tk0 = 2 * i;
        const int tk1 = 2 * i + 1;
        const bool full = (i < NITER - 1);

        // ===== P1: read Am0,Bn0(s0); stage Am1(b1,tk1); MFMA q0 =====
        READ_A0B0(s0);
        STAGE_A(1, tk1, 1);
        FENCE();
        LGKM_SB();
        __builtin_amdgcn_s_setprio(1);
        MFMA_Q0();
        __builtin_amdgcn_s_setprio(0);
        END_BARRIER();

        // ===== P2: read Bn1(s0); stage Am0(b0,tk0+2); MFMA q1 =====
        READ_B1(s0);
        if (full) STAGE_A(0, tk0 + 2, 0);
        FENCE();
        LGKM_SB();
        __builtin_amdgcn_s_setprio(1);
        MFMA_Q1();
        __builtin_amdgcn_s_setprio(0);
        END_BARRIER();

        // ===== P3: read Am1(s0); stage Bn0(b0,tk0+2); MFMA q2 =====
        READ_A1(s0);
        if (full) STAGE_B(0, tk0 + 2, 0);
        FENCE();
        LGKM_SB();
        __builtin_amdgcn_s_setprio(1);
        MFMA_Q2();
        __builtin_amdgcn_s_setprio(0);
        END_BARRIER();

        // ===== P4: stage Bn1(b0,tk0+2); MFMA q3; vmcnt(6) =====
        if (full) STAGE_B(0, tk0 + 2, 1);
        FENCE();
        __builtin_amdgcn_s_setprio(1);
        MFMA_Q3();
        __builtin_amdgcn_s_setprio(0);
        if (full) asm volatile("s_waitcnt vmcnt(6)" ::: "memory");
        else      asm volatile("s_waitcnt vmcnt(0)" ::: "memory");
        __builtin_amdgcn_sched_barrier(0);
        END_BARRIER();

        // ===== P5: read Am0,Bn0(s1); stage Am1(b0,tk0+2); MFMA q0 =====
        READ_A0B0(s1);
        if (full) STAGE_A(0, tk0 + 2, 1);
        FENCE();
        LGKM_SB();
        __builtin_amdgcn_s_setprio(1);
        MFMA_Q0();
        __builtin_amdgcn_s_setprio(0);
        END_BARRIER();

        // ===== P6: read Bn1(s1); stage Am0(b1,tk1+2); MFMA q1 =====
        READ_B1(s1);
        if (full) STAGE_A(1, tk1 + 2, 0);
        FENCE();
        LGKM_SB();
        __builtin_amdgcn_s_setprio(1);
        MFMA_Q1();
        __builtin_amdgcn_s_setprio(0);
        END_BARRIER();

        // ===== P7: read Am1(s1); stage Bn0(b1,tk1+2); MFMA q2 =====
        READ_A1(s1);
        if (full) STAGE_B(1, tk1 + 2, 0);
        FENCE();
        LGKM_SB();
        __builtin_amdgcn_s_setprio(1);
        MFMA_Q2();
        __builtin_amdgcn_s_setprio(0);
        END_BARRIER();

        // ===== P8: stage Bn1(b1,tk1+2); MFMA q3; vmcnt(6) =====
        if (full) STAGE_B(1, tk1 + 2, 1);
        FENCE();
        __builtin_amdgcn_s_setprio(1);
        MFMA_Q3();
        __builtin_amdgcn_s_setprio(0);
        if (full) asm volatile("s_waitcnt vmcnt(6)" ::: "memory");
        else      asm volatile("s_waitcnt vmcnt(0)" ::: "memory");
        __builtin_amdgcn_sched_barrier(0);
        END_BARRIER();
    }

#undef STAGE_A
#undef STAGE_B

    // epilogue: 32x32 C/D layout: col = l31, row = (reg&3)+8*(reg>>2)+4*hi
    const long cb = blockN + wc * 64;
    float bv[2];
    long  cn[2];
#pragma unroll
    for (int n = 0; n < 2; ++n) {
        cn[n] = cb + n * 32 + l31;
        bv[n] = bias[cn[n]];
    }
#pragma unroll
    for (int m = 0; m < 4; ++m) {
        const long r0 = blockM + wr * 128 + m * 32 + 4 * hi;
#pragma unroll
        for (int n = 0; n < 2; ++n)
#pragma unroll
            for (int j = 0; j < 16; ++j) {
                const long r = r0 + (j & 3) + 8 * (j >> 2);
                C[r * (long)N_DIM + cn[n]] = acc[m][n][j] + bv[n];
            }
    }
}

// ---------------- fp32 fallback (only if ws too small) ---------------------
__global__ void __launch_bounds__(256) gemm_f32_fallback(
    const float* __restrict__ A, const float* __restrict__ W,
    const float* __restrict__ bias, float* __restrict__ C)
{
    __shared__ float sA[64][17];
    __shared__ float sB[64][17];
    const int bm = blockIdx.y, bn = blockIdx.x;
    const int t = threadIdx.x;
    const int tx = t & 15, ty = t >> 4;
    const long row0 = (long)bm * 64, col0 = (long)bn * 64;
    float acc[4][4] = {};
    for (int kt = 0; kt < K_DIM; kt += 16) {
        const int r = t >> 2, c = (t & 3) * 4;
        float4 a4 = *(const float4*)&A[(row0 + r) * K_DIM + kt + c];
        float4 b4 = *(const float4*)&W[(col0 + r) * K_DIM + kt + c];
        sA[r][c] = a4.x; sA[r][c + 1] = a4.y; sA[r][c + 2] = a4.z; sA[r][c + 3] = a4.w;
        sB[r][c] = b4.x; sB[r][c + 1] = b4.y; sB[r][c + 2] = b4.z; sB[r][c + 3] = b4.w;
        __syncthreads();
#pragma unroll
        for (int kk = 0; kk < 16; ++kk) {
            float av[4], bv[4];
#pragma unroll
            for (int i = 0; i < 4; ++i) av[i] = sA[ty * 4 + i][kk];
#pragma unroll
            for (int j = 0; j < 4; ++j) bv[j] = sB[tx * 4 + j][kk];
#pragma unroll
            for (int i = 0; i < 4; ++i)
#pragma unroll
                for (int j = 0; j < 4; ++j) acc[i][j] += av[i] * bv[j];
        }
        __syncthreads();
    }
#pragma unroll
    for (int i = 0; i < 4; ++i)
#pragma unroll
        for (int j = 0; j < 4; ++j)
            C[(row0 + ty * 4 + i) * N_DIM + col0 + tx * 4 + j] =
                acc[i][j] + bias[col0 + tx * 4 + j];
}

extern "C" void kernel_launch(void* const* d_in, const int* in_sizes, int n_in,
                              void* d_out, int out_size, void* d_ws, size_t ws_size,
                              hipStream_t stream)
{
    const float* x = (const float*)d_in[0];   // [8192, 4096]
    const float* W = (const float*)d_in[1];   // [4096, 4096]
    const float* b = (const float*)d_in[2];   // [4096]
    float* out = (float*)d_out;               // [8192, 4096] fp32

    const long xe = (long)M_DIM * K_DIM;
    const long we = (long)N_DIM * K_DIM;
    const size_t need = (size_t)(xe + we) * sizeof(bf16_t);  // ~96 MiB

    if (ws_size >= need) {
        bf16_t* xb = (bf16_t*)d_ws;
        bf16_t* wb = xb + xe;
        cvt_f32_bf16<<<2048, 256, 0, stream>>>(x, xb, xe / 8);
        cvt_f32_bf16<<<1024, 256, 0, stream>>>(W, wb, we / 8);
        gemm_256_8ph<<<(M_DIM / 256) * (N_DIM / 256), 512, 0, stream>>>(xb, wb, b, out);
    } else {
        dim3 grid(N_DIM / 64, M_DIM / 64);
        gemm_f32_fallback<<<grid, 256, 0, stream>>>(x, W, b, out);
    }
}

// Round 9
// 266.282 us; speedup vs baseline: 1.1328x; 1.1328x over previous
//
#include <hip/hip_runtime.h>
#include <hip/hip_bf16.h>
#include <stdint.h>

// EvolvedLoopLinear: out[b,j] = sum_i x[b,i]*W[j,i] + b[j]
// M=8192, N=4096, K=4096. fp32 in/out, bf16 MFMA compute.
// Round 9: round-6 structure (16x16x32, 1 barrier/phase, counted vmcnt(6),
// XOR chunk swizzle, XCD swizzle, setprio) with the explicit lgkmcnt(0)
// before MFMA clusters REMOVED: every fragment read is consumed by
// same-phase MFMA, so the compiler's counted lgkmcnt waits retire reads
// in-phase (WAR publish preserved) while letting the MFMA front start
// after ~6 of 12 reads -> LDS-read window hides under the MFMA window.
// Reads ordered b-first; MFMA loops m{kk{n}} to consume earliest reads
// first. Barriers/fences/stage placement/vmcnt ledger identical to r6.

typedef __bf16 bf16_t;
typedef __bf16 bf16x8 __attribute__((ext_vector_type(8)));
typedef float  f32x4  __attribute__((ext_vector_type(4)));

#define M_DIM 8192
#define N_DIM 4096
#define K_DIM 4096
#define NT    (K_DIM / 64)    // 64 K-tiles of BK=64
#define NITER (NT / 2)        // 32 iterations, 2 K-tiles each

#define GLD16(gp, lp) __builtin_amdgcn_global_load_lds(                    \
    (const __attribute__((address_space(1))) void*)(gp),                   \
    (__attribute__((address_space(3))) void*)(lp), 16, 0, 0)

#define MFMA(a, b, c) __builtin_amdgcn_mfma_f32_16x16x32_bf16((a), (b), (c), 0, 0, 0)

#define FENCE() asm volatile("" ::: "memory")

// ---------------- fp32 -> bf16 convert (vectorized, grid-stride) -----------
__global__ void __launch_bounds__(256) cvt_f32_bf16(
    const float* __restrict__ in, bf16_t* __restrict__ out, long n8)
{
    long i0 = (long)blockIdx.x * blockDim.x + threadIdx.x;
    long stride = (long)gridDim.x * blockDim.x;
    for (long i = i0; i < n8; i += stride) {
        const float4* p = (const float4*)(in + i * 8);
        float4 a = p[0];
        float4 b = p[1];
        bf16x8 o;
        o[0] = (bf16_t)a.x; o[1] = (bf16_t)a.y; o[2] = (bf16_t)a.z; o[3] = (bf16_t)a.w;
        o[4] = (bf16_t)b.x; o[5] = (bf16_t)b.y; o[6] = (bf16_t)b.z; o[7] = (bf16_t)b.w;
        *(bf16x8*)(out + i * 8) = o;
    }
}

// ---------------- 256x256 8-phase bf16 GEMM (A,B row-major [*,K]) ----------
// LDS per parity buffer q (32768 el): Am0 @0, Am1 @8192, Bn0 @16384,
// Bn1 @24576. Chunk swizzle within each region: slot = chunk ^ (rho&7).
__global__ void __launch_bounds__(512, 1) gemm_256_8ph(
    const bf16_t* __restrict__ A, const bf16_t* __restrict__ B,
    const float* __restrict__ bias, float* __restrict__ C)
{
    __shared__ bf16_t sm[2 * 32768];   // 128 KiB

    // XCD-aware bijective swizzle (gridDim = 512, divisible by 8)
    const int nwg = gridDim.x;
    const int bid = blockIdx.x;
    const int cpx = nwg >> 3;
    const int swz = (bid & 7) * cpx + (bid >> 3);
    const int NBN = N_DIM / 256;                       // 16
    const long blockM = (long)(swz / NBN) * 256;
    const long blockN = (long)(swz % NBN) * 256;

    const int t    = threadIdx.x;
    const int lane = t & 63;
    const int wid  = t >> 6;        // 8 waves: 2 (M) x 4 (N)
    const int wr   = wid >> 2;      // 0..1 -> 128 rows each
    const int wc   = wid & 3;       // 0..3 -> 64 cols each
    const int l15  = lane & 15;
    const int lk   = lane >> 4;     // 0..3

    // staging: LDS dest linear (t*16B within region line); global src row
    // per region mapping, chunk carries inverse swizzle.
    const int cg  = (t & 7) ^ ((t >> 3) & 7);
    const int rA0 = (t >> 3);                                  // A line-0 row
    const int rB0 = ((t >> 3) & 31) | (((t >> 3) & 32) << 1);  // B line-0 row
    const bf16_t* gA = A + (blockM + rA0) * (long)K_DIM + cg * 8;
    const bf16_t* gB = B + (blockN + rB0) * (long)K_DIM + cg * 8;
    const int dstT = t * 8;         // 16 B per thread, linear within line

    // read side: fragment rho&7 == l15&7 for all fragments
    const int swzr = l15 & 7;
    const int cOff0 = ((0 * 4 + lk) ^ swzr) << 3;
    const int cOff1 = ((1 * 4 + lk) ^ swzr) << 3;
    const int aBase = wr * 4096 + l15 * 64;            // within Am region
    const int bBase = 16384 + wc * 2048 + l15 * 64;    // within buffer (Bn0)

    f32x4 acc[8][4] = {};

#define STAGE_A(q, tk, h) do {                                             \
    const bf16_t* _g = gA + (long)(tk) * 64 + (long)(h) * 64 * K_DIM;      \
    bf16_t* _l = (bf16_t*)sm + (q) * 32768 + (h) * 8192 + dstT;            \
    GLD16(_g,                _l);                                          \
    GLD16(_g + 128L * K_DIM, _l + 4096); } while (0)

#define STAGE_B(q, tk, h) do {                                             \
    const bf16_t* _g = gB + (long)(tk) * 64 + (long)(h) * 32 * K_DIM;      \
    bf16_t* _l = (bf16_t*)sm + (q) * 32768 + 16384 + (h) * 8192 + dstT;    \
    GLD16(_g,                _l);                                          \
    GLD16(_g + 128L * K_DIM, _l + 4096); } while (0)

    bf16x8 a0[4][2], a1[4][2], b0[2][2], b1[2][2];

    // reads issued b-first so the first MFMA group's operands land earliest;
    // no explicit lgkmcnt — compiler inserts counted waits per dependency.
#define READ_A0B0(s) do {                                                  \
    _Pragma("unroll") for (int n = 0; n < 2; ++n) {                        \
        b0[n][0] = *(const bf16x8*)((s) + bBase + n * 1024 + cOff0);       \
        b0[n][1] = *(const bf16x8*)((s) + bBase + n * 1024 + cOff1);       \
    }                                                                      \
    _Pragma("unroll") for (int m = 0; m < 4; ++m) {                        \
        a0[m][0] = *(const bf16x8*)((s) + aBase + m * 1024 + cOff0);       \
        a0[m][1] = *(const bf16x8*)((s) + aBase + m * 1024 + cOff1);       \
    } } while (0)

#define READ_B1(s) do {                                                    \
    _Pragma("unroll") for (int n = 0; n < 2; ++n) {                        \
        b1[n][0] = *(const bf16x8*)((s) + bBase + 8192 + n * 1024 + cOff0);\
        b1[n][1] = *(const bf16x8*)((s) + bBase + 8192 + n * 1024 + cOff1);\
    } } while (0)

#define READ_A1(s) do {                                                    \
    _Pragma("unroll") for (int m = 0; m < 4; ++m) {                        \
        a1[m][0] = *(const bf16x8*)((s) + 8192 + aBase + m * 1024 + cOff0);\
        a1[m][1] = *(const bf16x8*)((s) + 8192 + aBase + m * 1024 + cOff1);\
    } } while (0)

    // MFMA clusters: m-outer so group m only needs b(4 reads) + a[m](2);
    // kk-mid/n-inner keeps acc dep distance 2 with 8 independent accs.
#define MFMA_Q0() do { _Pragma("unroll") for (int m = 0; m < 4; ++m)       \
    _Pragma("unroll") for (int kk = 0; kk < 2; ++kk)                       \
    _Pragma("unroll") for (int n = 0; n < 2; ++n)                          \
        acc[m][n] = MFMA(a0[m][kk], b0[n][kk], acc[m][n]); } while (0)
#define MFMA_Q1() do { _Pragma("unroll") for (int m = 0; m < 4; ++m)       \
    _Pragma("unroll") for (int kk = 0; kk < 2; ++kk)                       \
    _Pragma("unroll") for (int n = 0; n < 2; ++n)                          \
        acc[m][2 + n] = MFMA(a0[m][kk], b1[n][kk], acc[m][2 + n]); } while (0)
#define MFMA_Q2() do { _Pragma("unroll") for (int m = 0; m < 4; ++m)       \
    _Pragma("unroll") for (int kk = 0; kk < 2; ++kk)                       \
    _Pragma("unroll") for (int n = 0; n < 2; ++n)                          \
        acc[4 + m][n] = MFMA(a1[m][kk], b0[n][kk], acc[4 + m][n]); } while (0)
#define MFMA_Q3() do { _Pragma("unroll") for (int m = 0; m < 4; ++m)       \
    _Pragma("unroll") for (int kk = 0; kk < 2; ++kk)                       \
    _Pragma("unroll") for (int n = 0; n < 2; ++n)                          \
        acc[4 + m][2 + n] = MFMA(a1[m][kk], b1[n][kk], acc[4 + m][2 + n]); } while (0)

#define END_BARRIER()                                                      \
    __builtin_amdgcn_s_barrier();                                          \
    FENCE()

    // prologue: tile0 all 4 regions (8 loads) | tile1 minus Am1 (6 loads).
    STAGE_A(0, 0, 0); STAGE_A(0, 0, 1); STAGE_B(0, 0, 0); STAGE_B(0, 0, 1);
    FENCE();
    STAGE_A(1, 1, 0); STAGE_B(1, 1, 0); STAGE_B(1, 1, 1);
    FENCE();
    asm volatile("s_waitcnt vmcnt(6)" ::: "memory");   // tile0 landed
    __builtin_amdgcn_sched_barrier(0);
    END_BARRIER();

    const bf16_t* s0 = (const bf16_t*)sm;           // buf0 (even tiles)
    const bf16_t* s1 = (const bf16_t*)sm + 32768;   // buf1 (odd tiles)

    for (int i = 0; i < NITER; ++i) {
        const int tk0 = 2 * i;
        const int tk1 = 2 * i + 1;
        const bool full = (i < NITER - 1);

        // ===== P1: read b0,a0(s0); stage Am1(b1,tk1); MFMA q0 =====
        READ_A0B0(s0);
        STAGE_A(1, tk1, 1);
        FENCE();
        __builtin_amdgcn_s_setprio(1);
        MFMA_Q0();
        __builtin_amdgcn_s_setprio(0);
        END_BARRIER();

        // ===== P2: read b1(s0); stage Am0(b0,tk0+2); MFMA q1 =====
        READ_B1(s0);
        if (full) STAGE_A(0, tk0 + 2, 0);
        FENCE();
        __builtin_amdgcn_s_setprio(1);
        MFMA_Q1();
        __builtin_amdgcn_s_setprio(0);
        END_BARRIER();

        // ===== P3: read a1(s0); stage Bn0(b0,tk0+2); MFMA q2 =====
        READ_A1(s0);
        if (full) STAGE_B(0, tk0 + 2, 0);
        FENCE();
        __builtin_amdgcn_s_setprio(1);
        MFMA_Q2();
        __builtin_amdgcn_s_setprio(0);
        END_BARRIER();

        // ===== P4: stage Bn1(b0,tk0+2); MFMA q3; vmcnt(6) =====
        if (full) STAGE_B(0, tk0 + 2, 1);
        FENCE();
        __builtin_amdgcn_s_setprio(1);
        MFMA_Q3();
        __builtin_amdgcn_s_setprio(0);
        if (full) asm volatile("s_waitcnt vmcnt(6)" ::: "memory");
        else      asm volatile("s_waitcnt vmcnt(0)" ::: "memory");
        __builtin_amdgcn_sched_barrier(0);
        END_BARRIER();

        // ===== P5: read b0,a0(s1); stage Am1(b0,tk0+2); MFMA q0 =====
        READ_A0B0(s1);
        if (full) STAGE_A(0, tk0 + 2, 1);
        FENCE();
        __builtin_amdgcn_s_setprio(1);
        MFMA_Q0();
        __builtin_amdgcn_s_setprio(0);
        END_BARRIER();

        // ===== P6: read b1(s1); stage Am0(b1,tk1+2); MFMA q1 =====
        READ_B1(s1);
        if (full) STAGE_A(1, tk1 + 2, 0);
        FENCE();
        __builtin_amdgcn_s_setprio(1);
        MFMA_Q1();
        __builtin_amdgcn_s_setprio(0);
        END_BARRIER();

        // ===== P7: read a1(s1); stage Bn0(b1,tk1+2); MFMA q2 =====
        READ_A1(s1);
        if (full) STAGE_B(1, tk1 + 2, 0);
        FENCE();
        __builtin_amdgcn_s_setprio(1);
        MFMA_Q2();
        __builtin_amdgcn_s_setprio(0);
        END_BARRIER();

        // ===== P8: stage Bn1(b1,tk1+2); MFMA q3; vmcnt(6) =====
        if (full) STAGE_B(1, tk1 + 2, 1);
        FENCE();
        __builtin_amdgcn_s_setprio(1);
        MFMA_Q3();
        __builtin_amdgcn_s_setprio(0);
        if (full) asm volatile("s_waitcnt vmcnt(6)" ::: "memory");
        else      asm volatile("s_waitcnt vmcnt(0)" ::: "memory");
        __builtin_amdgcn_sched_barrier(0);
        END_BARRIER();
    }

#undef STAGE_A
#undef STAGE_B

    // epilogue: C/D layout col = lane&15, row = (lane>>4)*4 + j
    const long cb = blockN + wc * 64;
    float bv[4];
    long  cn[4];
#pragma unroll
    for (int n = 0; n < 4; ++n) {
        cn[n] = cb + n * 16 + l15;
        bv[n] = bias[cn[n]];
    }
#pragma unroll
    for (int m = 0; m < 8; ++m) {
        const long r0 = blockM + wr * 128 + m * 16 + lk * 4;
#pragma unroll
        for (int n = 0; n < 4; ++n)
#pragma unroll
            for (int j = 0; j < 4; ++j)
                C[(r0 + j) * (long)N_DIM + cn[n]] = acc[m][n][j] + bv[n];
    }
}

// ---------------- fp32 fallback (only if ws too small) ---------------------
__global__ void __launch_bounds__(256) gemm_f32_fallback(
    const float* __restrict__ A, const float* __restrict__ W,
    const float* __restrict__ bias, float* __restrict__ C)
{
    __shared__ float sA[64][17];
    __shared__ float sB[64][17];
    const int bm = blockIdx.y, bn = blockIdx.x;
    const int t = threadIdx.x;
    const int tx = t & 15, ty = t >> 4;
    const long row0 = (long)bm * 64, col0 = (long)bn * 64;
    float acc[4][4] = {};
    for (int kt = 0; kt < K_DIM; kt += 16) {
        const int r = t >> 2, c = (t & 3) * 4;
        float4 a4 = *(const float4*)&A[(row0 + r) * K_DIM + kt + c];
        float4 b4 = *(const float4*)&W[(col0 + r) * K_DIM + kt + c];
        sA[r][c] = a4.x; sA[r][c + 1] = a4.y; sA[r][c + 2] = a4.z; sA[r][c + 3] = a4.w;
        sB[r][c] = b4.x; sB[r][c + 1] = b4.y; sB[r][c + 2] = b4.z; sB[r][c + 3] = b4.w;
        __syncthreads();
#pragma unroll
        for (int kk = 0; kk < 16; ++kk) {
            float av[4], bv[4];
#pragma unroll
            for (int i = 0; i < 4; ++i) av[i] = sA[ty * 4 + i][kk];
#pragma unroll
            for (int j = 0; j < 4; ++j) bv[j] = sB[tx * 4 + j][kk];
#pragma unroll
            for (int i = 0; i < 4; ++i)
#pragma unroll
                for (int j = 0; j < 4; ++j) acc[i][j] += av[i] * bv[j];
        }
        __syncthreads();
    }
#pragma unroll
    for (int i = 0; i < 4; ++i)
#pragma unroll
        for (int j = 0; j < 4; ++j)
            C[(row0 + ty * 4 + i) * N_DIM + col0 + tx * 4 + j] =
                acc[i][j] + bias[col0 + tx * 4 + j];
}

extern "C" void kernel_launch(void* const* d_in, const int* in_sizes, int n_in,
                              void* d_out, int out_size, void* d_ws, size_t ws_size,
                              hipStream_t stream)
{
    const float* x = (const float*)d_in[0];   // [8192, 4096]
    const float* W = (const float*)d_in[1];   // [4096, 4096]
    const float* b = (const float*)d_in[2];   // [4096]
    float* out = (float*)d_out;               // [8192, 4096] fp32

    const long xe = (long)M_DIM * K_DIM;
    const long we = (long)N_DIM * K_DIM;
    const size_t need = (size_t)(xe + we) * sizeof(bf16_t);  // ~96 MiB

    if (ws_size >= need) {
        bf16_t* xb = (bf16_t*)d_ws;
        bf16_t* wb = xb + xe;
        cvt_f32_bf16<<<2048, 256, 0, stream>>>(x, xb, xe / 8);
        cvt_f32_bf16<<<1024, 256, 0, stream>>>(W, wb, we / 8);
        gemm_256_8ph<<<(M_DIM / 256) * (N_DIM / 256), 512, 0, stream>>>(xb, wb, b, out);
    } else {
        dim3 grid(N_DIM / 64, M_DIM / 64);
        gemm_f32_fallback<<<grid, 256, 0, stream>>>(x, W, b, out);
    }
}